// Round 10
// baseline (204.068 us; speedup 1.0000x reference)
//
#include <hip/hip_runtime.h>
#include <stdint.h>

#define IN_DIM 1024
#define H_DIM  1024
#define BATCH  8192
#define KDIM   2048   // IN + H
#define NDIM   4096   // 4*H
#define BM     256
#define BN     256
#define BK     64
#define NT     (KDIM / BK)   // 32 K-tiles

typedef __bf16 bf16x8 __attribute__((ext_vector_type(8)));
typedef float  f32x16 __attribute__((ext_vector_type(16)));
typedef unsigned int u32;

static __device__ __forceinline__ unsigned short f2bf(float f) {
  u32 u = __builtin_bit_cast(u32, f);
  u += 0x7FFFu + ((u >> 16) & 1u);   // round-to-nearest-even
  return (unsigned short)(u >> 16);
}

static __device__ __forceinline__ float sigm(float x) {
  return 1.0f / (1.0f + __expf(-x));
}
static __device__ __forceinline__ float tanh_fast(float x) {
  float e = __expf(-2.0f * fabsf(x));     // in (0,1], no overflow
  float t = (1.0f - e) / (1.0f + e);
  return copysignf(t, x);
}

// ---------------- prep 1: A = [x | h] -> bf16 [BATCH][KDIM] ----------------
__global__ void conv_a(const float* __restrict__ x, const float* __restrict__ h,
                       unsigned short* __restrict__ A) {
  const int total = BATCH * KDIM / 4;
  for (int i = blockIdx.x * blockDim.x + threadIdx.x; i < total;
       i += gridDim.x * blockDim.x) {
    int b = i >> 9;              // 512 quads per row
    int k = (i & 511) << 2;
    const float* src = (k < IN_DIM) ? (x + (size_t)b * IN_DIM + k)
                                    : (h + (size_t)b * H_DIM + (k - IN_DIM));
    float4 v = *reinterpret_cast<const float4*>(src);
    ushort4 o;
    o.x = f2bf(v.x); o.y = f2bf(v.y); o.z = f2bf(v.z); o.w = f2bf(v.w);
    *reinterpret_cast<ushort4*>(A + (size_t)b * KDIM + k) = o;
  }
}

// ---- prep 2: Bt[j][k] = W[k][c], bf16. Gate-contiguous permutation:
//      c = g*1024 + u  ->  j = (u>>4)*64 + g*16 + (u&15)
__global__ void conv_b(const float* __restrict__ Wi, const float* __restrict__ Wh,
                       unsigned short* __restrict__ Bt) {
  __shared__ float tile[32][33];
  int k0 = blockIdx.x * 32;            // 0..2047 (k of combined [Wi;Wh])
  int c0 = blockIdx.y * 32;            // 0..4095 (orig col)
  int tx = threadIdx.x;                // 0..31
  int ty = threadIdx.y;                // 0..7
  const float* src = (k0 < IN_DIM) ? (Wi + (size_t)k0 * NDIM)
                                   : (Wh + (size_t)(k0 - IN_DIM) * NDIM);
  for (int i = 0; i < 4; i++) {
    int r = ty + 8 * i;
    tile[r][tx] = src[(size_t)r * NDIM + c0 + tx];
  }
  __syncthreads();
  int g = c0 >> 10;                    // gate index (tile doesn't straddle)
  int ubase = c0 & 1023;
  for (int i = 0; i < 4; i++) {
    int cc = ty + 8 * i;
    int u = ubase + cc;
    int j = ((u >> 4) << 6) + (g << 4) + (u & 15);
    Bt[(size_t)j * KDIM + k0 + tx] = f2bf(tile[tx][cc]);
  }
}

// ---------------- prep 3: bias[j] = bi[c(j)] + bh[c(j)] ----------------
__global__ void conv_bias(const float* __restrict__ bi, const float* __restrict__ bh,
                          float* __restrict__ bias) {
  int j = blockIdx.x * blockDim.x + threadIdx.x;
  if (j < NDIM) {
    int u = ((j >> 6) << 4) + (j & 15);
    int g = (j >> 4) & 3;
    int c = (g << 10) + u;
    bias[j] = bi[c] + bh[c];
  }
}

// ------- 256x256 GEMM (32x32x16 MFMA), 2-barrier/K-tile + fused epilogue -----
static __device__ __forceinline__ void gload_lds16(const void* g, void* l) {
  __builtin_amdgcn_global_load_lds(
      (const __attribute__((address_space(1))) u32*)g,
      (__attribute__((address_space(3))) u32*)l, 16, 0, 0);
}

#define MFMA32 __builtin_amdgcn_mfma_f32_32x32x16_bf16
#define SGB  __builtin_amdgcn_sched_group_barrier
// LLVM SchedGroupMask: MFMA=0x8, DS_READ=0x100

__launch_bounds__(512, 2)
__global__ void lstm_gemm(const unsigned short* __restrict__ A,
                          const unsigned short* __restrict__ Bt,
                          const float* __restrict__ bias,
                          const float* __restrict__ Cin,
                          float* __restrict__ Hout,
                          float* __restrict__ Cout) {
  // LDS: A [2 buf][2 half][128 rows][128B] = 64K | B same = 64K  (128 KiB)
  __shared__ __align__(16) char smem[131072];

  const int t  = threadIdx.x;
  const int l  = t & 63;
  const int w  = t >> 6;           // wave 0-7
  const int l31 = l & 31;
  const int wr = w >> 2;           // 0-1  (M)
  const int wc = w & 3;            // 0-3  (N)

  int bid = blockIdx.x;            // 512 blocks (32 M-tiles x 16 N-tiles)
  int swz = (bid & 7) * 64 + (bid >> 3);   // bijective XCD swizzle (512%8==0)
  int brow = (swz >> 4) * BM;
  int bcol = (swz & 15) * BN;

  // ---- staging: slot=(w*2+q)*64+l, LDS linear slot*16; global source chunk
  //      pre-swizzled c = (slot&7) ^ (row&7)  (read side XORs the same) ----
  int slot0 = w * 128 + l, slot1 = slot0 + 64;
  int rih0 = slot0 >> 3, rih1 = slot1 >> 3;
  int c0 = (slot0 & 7) ^ (rih0 & 7), c1 = (slot1 & 7) ^ (rih1 & 7);

  // 8 rolling global pointers (A/B x half0/1 x slot q0/q1), bumped 64 elem/K-tile
  const unsigned short* a0q0 = A + (size_t)(brow + (rih0 >> 6) * 128 + (rih0 & 63)) * KDIM + c0 * 8;
  const unsigned short* a0q1 = A + (size_t)(brow + (rih1 >> 6) * 128 + (rih1 & 63)) * KDIM + c1 * 8;
  const unsigned short* a1q0 = a0q0 + 131072;   // +64 rows
  const unsigned short* a1q1 = a0q1 + 131072;
  const unsigned short* b0q0 = Bt + (size_t)(bcol + (rih0 >> 5) * 64 + (rih0 & 31)) * KDIM + c0 * 8;
  const unsigned short* b0q1 = Bt + (size_t)(bcol + (rih1 >> 5) * 64 + (rih1 & 31)) * KDIM + c1 * 8;
  const unsigned short* b1q0 = b0q0 + 65536;    // +32 rows
  const unsigned short* b1q1 = b0q1 + 65536;

#define GL(gp, loff) gload_lds16((gp), smem + (loff) + w * 2048 + l * 16)

  // ---- per-lane ds_read bases for 32x32x16 fragments:
  //      A row = l&31 (within 32-row tile), k-16B-chunk kb = l>>5;
  //      swizzled chunk(s) = (2s + kb) ^ (l&7)  ->  4 bases, one per k-step ----
  const int q4 = ((l >> 5) ^ (l & 7)) << 4;      // (kb ^ row&7) << 4
  char* vA_s[4];
  char* vB_s[4];
#pragma unroll
  for (int s = 0; s < 4; s++) {
    int off = ((s << 5) ^ q4);                   // ((2s)^q)<<4, bits disjoint-safe
    vA_s[s] = smem + (wr * 64 + l31) * 128 + off;
    vB_s[s] = smem + 65536 + (wc * 32 + l31) * 128 + off;
  }
  // frag addr: A(P,mt,s) = vA_s[s] + P*32768 + (mt>>1)*16384 + (mt&1)*4096
  //            B(P,nt,s) = vB_s[s] + P*32768 + nt*16384

  f32x16 acc[4][2];
#pragma unroll
  for (int m = 0; m < 4; m++)
#pragma unroll
    for (int n = 0; n < 2; n++)
#pragma unroll
      for (int r = 0; r < 16; r++) acc[m][n][r] = 0.f;

  // ---- prologue: tile0 full -> buf0 ; tile1 {A0,B0} -> buf1 ----
  GL(a0q0, 0);                 GL(a0q1, 1024);
  GL(b0q0, 65536);             GL(b0q1, 65536 + 1024);
  GL(a1q0, 16384);             GL(a1q1, 16384 + 1024);
  GL(b1q0, 65536 + 16384);     GL(b1q1, 65536 + 16384 + 1024);
  GL(a0q0 + 64, 32768);        GL(a0q1 + 64, 32768 + 1024);
  GL(b0q0 + 64, 65536 + 32768);GL(b0q1 + 64, 65536 + 32768 + 1024);
  asm volatile("s_waitcnt vmcnt(4)" ::: "memory");   // tile0 landed
  __builtin_amdgcn_s_barrier();
  __builtin_amdgcn_sched_barrier(0);
  GL(a1q0 + 64, 32768 + 16384); GL(a1q1 + 64, 32768 + 16384 + 1024);

  // ---- operand registers ----
  bf16x8 afrA[2][4], afrB[2][4], bfrN0[4], bfrN1[4];

  // prime: afrA = A[mt0,mt1][s], bfrN0 = B[N0][s] from buf0
#pragma unroll
  for (int s = 0; s < 4; s++) {
    afrA[0][s] = *(const bf16x8*)(vA_s[s]);
    afrA[1][s] = *(const bf16x8*)(vA_s[s] + 4096);
    bfrN0[s]   = *(const bf16x8*)(vB_s[s]);
  }
  // roll: a*,b0 -> tile2 ; b1 -> tile1
  a0q0 += 128; a0q1 += 128; a1q0 += 128; a1q1 += 128;
  b0q0 += 128; b0q1 += 128; b1q0 += 64;  b1q1 += 64;

  // ---- 2-barrier K-tile body (hazard schedule identical to R9) ----
#define BODY(P)                                                              \
  {                                                                          \
    /* S1: stage B1(t+1) -> buf^1 */                                         \
    GL(b1q0, 65536 + ((P)^1)*32768 + 16384);                                 \
    GL(b1q1, 65536 + ((P)^1)*32768 + 16384 + 1024);                          \
    /* Q1: MFMA(afrA x bfrN0 -> acc[0..1][0]) ∥ read bfrN1(t) */             \
    __builtin_amdgcn_s_setprio(1);                                           \
    _Pragma("unroll") for (int s = 0; s < 4; s++)                            \
      bfrN1[s] = *(const bf16x8*)(vB_s[s] + (P)*32768 + 16384);              \
    _Pragma("unroll") for (int s = 0; s < 4; s++)                            \
      _Pragma("unroll") for (int mt = 0; mt < 2; mt++)                       \
        acc[mt][0] = MFMA32(afrA[mt][s], bfrN0[s], acc[mt][0], 0, 0, 0);     \
    SGB(0x100, 1, 0); SGB(0x8, 2, 0);                                        \
    SGB(0x100, 1, 0); SGB(0x8, 2, 0);                                        \
    SGB(0x100, 1, 0); SGB(0x8, 2, 0);                                        \
    SGB(0x100, 1, 0); SGB(0x8, 2, 0);                                        \
    __builtin_amdgcn_s_setprio(0);                                           \
    __builtin_amdgcn_s_barrier();          /* bar_A */                       \
    __builtin_amdgcn_sched_barrier(0);                                       \
    /* S2: stage A0(t+2) -> buf P */                                         \
    GL(a0q0, (P)*32768);                                                     \
    GL(a0q1, (P)*32768 + 1024);                                              \
    /* Q2: MFMA(afrA x bfrN1 -> acc[0..1][1]) ∥ read afrB = A[mt2,mt3](t) */ \
    __builtin_amdgcn_s_setprio(1);                                           \
    _Pragma("unroll") for (int s = 0; s < 4; s++) {                          \
      afrB[0][s] = *(const bf16x8*)(vA_s[s] + (P)*32768 + 16384);            \
      afrB[1][s] = *(const bf16x8*)(vA_s[s] + (P)*32768 + 16384 + 4096);     \
    }                                                                        \
    _Pragma("unroll") for (int s = 0; s < 4; s++)                            \
      _Pragma("unroll") for (int mt = 0; mt < 2; mt++)                       \
        acc[mt][1] = MFMA32(afrA[mt][s], bfrN1[s], acc[mt][1], 0, 0, 0);     \
    SGB(0x100, 1, 0); SGB(0x8, 1, 0);                                        \
    SGB(0x100, 1, 0); SGB(0x8, 1, 0);                                        \
    SGB(0x100, 1, 0); SGB(0x8, 1, 0);                                        \
    SGB(0x100, 1, 0); SGB(0x8, 1, 0);                                        \
    SGB(0x100, 1, 0); SGB(0x8, 1, 0);                                        \
    SGB(0x100, 1, 0); SGB(0x8, 1, 0);                                        \
    SGB(0x100, 1, 0); SGB(0x8, 1, 0);                                        \
    SGB(0x100, 1, 0); SGB(0x8, 1, 0);                                        \
    __builtin_amdgcn_s_setprio(0);                                           \
    /* S3: stage B0(t+2) -> buf P */                                         \
    GL(b0q0, 65536 + (P)*32768);                                             \
    GL(b0q1, 65536 + (P)*32768 + 1024);                                      \
    /* Q3: MFMA(afrB x bfrN0 -> acc[2..3][0]), register-only */              \
    __builtin_amdgcn_s_setprio(1);                                           \
    _Pragma("unroll") for (int s = 0; s < 4; s++)                            \
      _Pragma("unroll") for (int mt = 0; mt < 2; mt++)                       \
        acc[2+mt][0] = MFMA32(afrB[mt][s], bfrN0[s], acc[2+mt][0], 0, 0, 0); \
    __builtin_amdgcn_s_setprio(0);                                           \
    /* gate: tile t+1 fully landed (only A0,B0(t+2) stay outstanding) */     \
    asm volatile("s_waitcnt vmcnt(4)" ::: "memory");                         \
    __builtin_amdgcn_s_barrier();          /* bar_B */                       \
    __builtin_amdgcn_sched_barrier(0);                                       \
    /* S4: stage A1(t+2) -> buf P */                                         \
    GL(a1q0, (P)*32768 + 16384);                                             \
    GL(a1q1, (P)*32768 + 16384 + 1024);                                      \
    /* Q4: MFMA(afrB x bfrN1 -> acc[2..3][1]) ∥ read afrA,bfrN0 of t+1 */    \
    __builtin_amdgcn_s_setprio(1);                                           \
    _Pragma("unroll") for (int s = 0; s < 4; s++) {                          \
      afrA[0][s] = *(const bf16x8*)(vA_s[s] + ((P)^1)*32768);                \
      afrA[1][s] = *(const bf16x8*)(vA_s[s] + ((P)^1)*32768 + 4096);         \
      bfrN0[s]   = *(const bf16x8*)(vB_s[s] + ((P)^1)*32768);                \
    }                                                                        \
    _Pragma("unroll") for (int s = 0; s < 4; s++)                            \
      _Pragma("unroll") for (int mt = 0; mt < 2; mt++)                       \
        acc[2+mt][1] = MFMA32(afrB[mt][s], bfrN1[s], acc[2+mt][1], 0, 0, 0); \
    SGB(0x100, 3, 0); SGB(0x8, 2, 0);                                        \
    SGB(0x100, 3, 0); SGB(0x8, 2, 0);                                        \
    SGB(0x100, 3, 0); SGB(0x8, 2, 0);                                        \
    SGB(0x100, 3, 0); SGB(0x8, 2, 0);                                        \
    __builtin_amdgcn_s_setprio(0);                                           \
    a0q0 += 64; a0q1 += 64; a1q0 += 64; a1q1 += 64;                          \
    b0q0 += 64; b0q1 += 64; b1q0 += 64; b1q1 += 64;                          \
  }

  for (int it = 0; it < NT / 2; ++it) {
    BODY(0)
    BODY(1)
  }
#undef BODY
#undef GL

  // ---- drain outstanding staging loads (also orders Cin/bias below) ----
  asm volatile("s_waitcnt vmcnt(0)" ::: "memory");

  // ---- epilogue (32x32 C/D layout: col = l&31, row = (r&3)+8(r>>2)+4(l>>5)):
  //      lane l&16==0 holds {I,G}, lane l&16 holds {F,O} of unit U;
  //      one shfl_xor(16) passes I*G to the F/O lane. Register-resident. ----
  const float bv0 = bias[bcol + 64 * wc + l31];        // nt0 gate (I or F)
  const float bv1 = bias[bcol + 64 * wc + 32 + l31];   // nt1 gate (G or O)
  const bool hi = (l & 16) != 0;
  const int U = (bcol >> 2) + wc * 16 + (l & 15);
  const int rbase = brow + wr * 128 + 4 * (l >> 5);

#pragma unroll
  for (int mt = 0; mt < 4; mt++)
#pragma unroll
    for (int r = 0; r < 16; r++) {
      float g0 = acc[mt][0][r] + bv0;
      float g1 = acc[mt][1][r] + bv1;
      float IG = sigm(g0) * tanh_fast(g1);     // meaningful on low lanes
      float P  = __shfl_xor(IG, 16);           // high lanes receive I*G
      if (hi) {
        int row = rbase + mt * 32 + (r & 3) + 8 * (r >> 2);
        size_t idx = (size_t)row * H_DIM + U;
        float F = sigm(g0);
        float O = sigm(g1);
        float cn = F * Cin[idx] + P;
        Hout[idx] = O * tanh_fast(cn);
        Cout[idx] = cn;
      }
    }
}

extern "C" void kernel_launch(void* const* d_in, const int* in_sizes, int n_in,
                              void* d_out, int out_size, void* d_ws, size_t ws_size,
                              hipStream_t stream) {
  const float* x  = (const float*)d_in[0];
  const float* h  = (const float*)d_in[1];
  const float* c  = (const float*)d_in[2];
  const float* Wi = (const float*)d_in[3];
  const float* bi = (const float*)d_in[4];
  const float* Wh = (const float*)d_in[5];
  const float* bh = (const float*)d_in[6];

  float* out  = (float*)d_out;
  float* Hout = out;
  float* Cout = out + (size_t)BATCH * H_DIM;

  // workspace layout: A bf16 (32 MiB) | Bt bf16 (16 MiB) | bias f32 (16 KiB)
  unsigned short* Abf = (unsigned short*)d_ws;
  unsigned short* Btb = (unsigned short*)((char*)d_ws + 33554432);
  float*          bsf = (float*)((char*)d_ws + 50331648);

  conv_a<<<2048, 256, 0, stream>>>(x, h, Abf);
  conv_b<<<dim3(64, 128), dim3(32, 8), 0, stream>>>(Wi, Wh, Btb);
  conv_bias<<<16, 256, 0, stream>>>(bi, bh, bsf);
  lstm_gemm<<<512, 512, 0, stream>>>(Abf, Btb, bsf, c, Hout, Cout);
}

// Round 11
// 157.303 us; speedup vs baseline: 1.2973x; 1.2973x over previous
//
#include <hip/hip_runtime.h>
#include <stdint.h>

#define IN_DIM 1024
#define H_DIM  1024
#define BATCH  8192
#define KDIM   2048   // IN + H
#define NDIM   4096   // 4*H
#define BM     256
#define BN     256
#define BK     64
#define NT     (KDIM / BK)   // 32 K-tiles

typedef __bf16 bf16x8 __attribute__((ext_vector_type(8)));
typedef float  f32x4  __attribute__((ext_vector_type(4)));
typedef unsigned int u32;

static __device__ __forceinline__ unsigned short f2bf(float f) {
  u32 u = __builtin_bit_cast(u32, f);
  u += 0x7FFFu + ((u >> 16) & 1u);   // round-to-nearest-even
  return (unsigned short)(u >> 16);
}

static __device__ __forceinline__ float sigm(float x) {
  return 1.0f / (1.0f + __expf(-x));
}
static __device__ __forceinline__ float tanh_fast(float x) {
  float e = __expf(-2.0f * fabsf(x));     // in (0,1], no overflow
  float t = (1.0f - e) / (1.0f + e);
  return copysignf(t, x);
}

// ---------------- prep 1: A = [x | h] -> bf16 [BATCH][KDIM] ----------------
__global__ void conv_a(const float* __restrict__ x, const float* __restrict__ h,
                       unsigned short* __restrict__ A) {
  const int total = BATCH * KDIM / 4;
  for (int i = blockIdx.x * blockDim.x + threadIdx.x; i < total;
       i += gridDim.x * blockDim.x) {
    int b = i >> 9;              // 512 quads per row
    int k = (i & 511) << 2;
    const float* src = (k < IN_DIM) ? (x + (size_t)b * IN_DIM + k)
                                    : (h + (size_t)b * H_DIM + (k - IN_DIM));
    float4 v = *reinterpret_cast<const float4*>(src);
    ushort4 o;
    o.x = f2bf(v.x); o.y = f2bf(v.y); o.z = f2bf(v.z); o.w = f2bf(v.w);
    *reinterpret_cast<ushort4*>(A + (size_t)b * KDIM + k) = o;
  }
}

// ---- prep 2: Bt[j][k] = W[k][c], bf16. Gate-contiguous permutation:
//      c = g*1024 + u  ->  j = (u>>4)*64 + g*16 + (u&15)
//      so fragment nn of wave wc holds gate nn of unit (bcol>>2)+wc*16+lane16
__global__ void conv_b(const float* __restrict__ Wi, const float* __restrict__ Wh,
                       unsigned short* __restrict__ Bt) {
  __shared__ float tile[32][33];
  int k0 = blockIdx.x * 32;            // 0..2047 (k of combined [Wi;Wh])
  int c0 = blockIdx.y * 32;            // 0..4095 (orig col)
  int tx = threadIdx.x;                // 0..31
  int ty = threadIdx.y;                // 0..7
  const float* src = (k0 < IN_DIM) ? (Wi + (size_t)k0 * NDIM)
                                   : (Wh + (size_t)(k0 - IN_DIM) * NDIM);
  for (int i = 0; i < 4; i++) {
    int r = ty + 8 * i;
    tile[r][tx] = src[(size_t)r * NDIM + c0 + tx];
  }
  __syncthreads();
  int g = c0 >> 10;                    // gate index (tile doesn't straddle)
  int ubase = c0 & 1023;
  for (int i = 0; i < 4; i++) {
    int cc = ty + 8 * i;
    int u = ubase + cc;
    int j = ((u >> 4) << 6) + (g << 4) + (u & 15);
    Bt[(size_t)j * KDIM + k0 + tx] = f2bf(tile[tx][cc]);
  }
}

// ---------------- prep 3: bias[j] = bi[c(j)] + bh[c(j)] ----------------
__global__ void conv_bias(const float* __restrict__ bi, const float* __restrict__ bh,
                          float* __restrict__ bias) {
  int j = blockIdx.x * blockDim.x + threadIdx.x;
  if (j < NDIM) {
    int u = ((j >> 6) << 4) + (j & 15);
    int g = (j >> 4) & 3;
    int c = (g << 10) + u;
    bias[j] = bi[c] + bh[c];
  }
}

// ------- 256x256 GEMM, 2-barrier/K-tile pipeline + fused LSTM epilogue -------
static __device__ __forceinline__ void gload_lds16(const void* g, void* l) {
  __builtin_amdgcn_global_load_lds(
      (const __attribute__((address_space(1))) u32*)g,
      (__attribute__((address_space(3))) u32*)l, 16, 0, 0);
}

#define MFMA __builtin_amdgcn_mfma_f32_16x16x32_bf16
#define SGB  __builtin_amdgcn_sched_group_barrier
// LLVM SchedGroupMask: MFMA=0x8, DS_READ=0x100

__launch_bounds__(512, 2)
__global__ void lstm_gemm(const unsigned short* __restrict__ A,
                          const unsigned short* __restrict__ Bt,
                          const float* __restrict__ bias,
                          const float* __restrict__ Cin,
                          float* __restrict__ Hout,
                          float* __restrict__ Cout) {
  // LDS: A [2 buf][2 half][128 rows][128B] = 64K | B same = 64K  (128 KiB)
  __shared__ __align__(16) char smem[131072];

  const int t  = threadIdx.x;
  const int l  = t & 63;
  const int w  = t >> 6;           // wave 0-7
  const int lane16 = l & 15;
  const int kg = l >> 4;           // 0-3
  const int wr = w >> 2;           // 0-1  (M)
  const int wc = w & 3;            // 0-3  (N)

  int bid = blockIdx.x;            // 512 blocks (32 M-tiles x 16 N-tiles)
  int swz = (bid & 7) * 64 + (bid >> 3);   // bijective XCD swizzle (512%8==0)
  int brow = (swz >> 4) * BM;
  int bcol = (swz & 15) * BN;

  // ---- staging: slot=(w*2+q)*64+l, LDS linear slot*16; global source chunk
  //      pre-swizzled c = (slot&7) ^ (row&7)  (read side XORs the same) ----
  int slot0 = w * 128 + l, slot1 = slot0 + 64;
  int rih0 = slot0 >> 3, rih1 = slot1 >> 3;
  int c0 = (slot0 & 7) ^ (rih0 & 7), c1 = (slot1 & 7) ^ (rih1 & 7);

  // 8 rolling global pointers (A/B x half0/1 x slot q0/q1), bumped 64 elem/K-tile
  const unsigned short* a0q0 = A + (size_t)(brow + (rih0 >> 6) * 128 + (rih0 & 63)) * KDIM + c0 * 8;
  const unsigned short* a0q1 = A + (size_t)(brow + (rih1 >> 6) * 128 + (rih1 & 63)) * KDIM + c1 * 8;
  const unsigned short* a1q0 = a0q0 + 131072;   // +64 rows
  const unsigned short* a1q1 = a0q1 + 131072;
  const unsigned short* b0q0 = Bt + (size_t)(bcol + (rih0 >> 5) * 64 + (rih0 & 31)) * KDIM + c0 * 8;
  const unsigned short* b0q1 = Bt + (size_t)(bcol + (rih1 >> 5) * 64 + (rih1 & 31)) * KDIM + c1 * 8;
  const unsigned short* b1q0 = b0q0 + 65536;    // +32 rows
  const unsigned short* b1q1 = b0q1 + 65536;

#define GL(gp, loff) gload_lds16((gp), smem + (loff) + w * 2048 + l * 16)

  // ---- per-lane ds_read base addresses; everything else folds to offset: ----
  const int msk = (lane16 & 7) << 4;
  char* vA0 = smem + wr * 8192 + lane16 * 128 + ((kg * 16) ^ msk);
  char* vA1 = smem + wr * 8192 + lane16 * 128 + ((64 + kg * 16) ^ msk);
  char* vB0 = smem + 65536 + wc * 4096 + lane16 * 128 + ((kg * 16) ^ msk);
  char* vB1 = smem + 65536 + wc * 4096 + lane16 * 128 + ((64 + kg * 16) ^ msk);

  f32x4 acc[8][4];
#pragma unroll
  for (int m = 0; m < 8; m++)
#pragma unroll
    for (int n = 0; n < 4; n++) acc[m][n] = (f32x4){0.f, 0.f, 0.f, 0.f};

  // ---- prologue: tiles 0 AND 1 fully staged (B1 now distance-2, R11) ----
  GL(a0q0, 0);                 GL(a0q1, 1024);
  GL(b0q0, 65536);             GL(b0q1, 65536 + 1024);
  GL(a1q0, 16384);             GL(a1q1, 16384 + 1024);
  GL(b1q0, 65536 + 16384);     GL(b1q1, 65536 + 16384 + 1024);
  GL(a0q0 + 64, 32768);        GL(a0q1 + 64, 32768 + 1024);
  GL(b0q0 + 64, 65536 + 32768);GL(b0q1 + 64, 65536 + 32768 + 1024);
  GL(a1q0 + 64, 32768 + 16384);GL(a1q1 + 64, 32768 + 16384 + 1024);
  GL(b1q0 + 64, 65536 + 32768 + 16384);
  GL(b1q1 + 64, 65536 + 32768 + 16384 + 1024);
  asm volatile("s_waitcnt vmcnt(8)" ::: "memory");   // tile0 landed
  __builtin_amdgcn_s_barrier();
  __builtin_amdgcn_sched_barrier(0);

  // ---- operand registers (ping-pong lifetimes across quadrant clusters) ----
  bf16x8 afrA[4][2], afrB[4][2], bfr[4][2];

  // prime: afrA = A0(0), bfr01 = B0(0) from buf0
#pragma unroll
  for (int mm = 0; mm < 4; mm++) {
    afrA[mm][0] = *(const bf16x8*)(vA0 + mm * 2048);
    afrA[mm][1] = *(const bf16x8*)(vA1 + mm * 2048);
  }
#pragma unroll
  for (int nn = 0; nn < 2; nn++) {
    bfr[nn][0] = *(const bf16x8*)(vB0 + nn * 2048);
    bfr[nn][1] = *(const bf16x8*)(vB1 + nn * 2048);
  }
  // roll: all pointers -> tile2 (every region now staged at distance 2)
  a0q0 += 128; a0q1 += 128; a1q0 += 128; a1q1 += 128;
  b0q0 += 128; b0q1 += 128; b1q0 += 128; b1q1 += 128;

  // ---- 2-barrier K-tile body. Sync points: bar_A (after Q1 cluster) and
  //      vmcnt(6)+bar_B (before Q4 cluster). All four tile regions staged at
  //      distance 2 -> every load gated by vmcnt(6) aged a full iteration
  //      (~2800 cy >> HBM latency): no residual stall. Hazards:
  //      buf-P B1 overwritten at S2 only after Q1 reads it (bar_A fences);
  //      buf-P A0/B0 overwritten after their tile-t reads (Q1/Q2 clusters);
  //      buf-P A1 overwritten at S4 after bar_B. sched_barrier(0) after each
  //      barrier stops GL/ds_read hoisting (rule #18).
#define BODY(P)                                                              \
  {                                                                          \
    /* Q1 cluster: MFMA(afrA,bfr01) ∥ read bfr23(t) */                       \
    __builtin_amdgcn_s_setprio(1);                                           \
    _Pragma("unroll") for (int nn = 2; nn < 4; nn++) {                       \
      bfr[nn][0] = *(const bf16x8*)(vB0 + (P)*32768 + 16384 + (nn-2)*2048);  \
      bfr[nn][1] = *(const bf16x8*)(vB1 + (P)*32768 + 16384 + (nn-2)*2048);  \
    }                                                                        \
    _Pragma("unroll") for (int mm = 0; mm < 4; mm++)                         \
      _Pragma("unroll") for (int nn = 0; nn < 2; nn++) {                     \
        acc[mm][nn] = MFMA(afrA[mm][0], bfr[nn][0], acc[mm][nn], 0, 0, 0);   \
        acc[mm][nn] = MFMA(afrA[mm][1], bfr[nn][1], acc[mm][nn], 0, 0, 0);   \
      }                                                                      \
    SGB(0x100, 1, 0); SGB(0x8, 4, 0);                                        \
    SGB(0x100, 1, 0); SGB(0x8, 4, 0);                                        \
    SGB(0x100, 1, 0); SGB(0x8, 4, 0);                                        \
    SGB(0x100, 1, 0); SGB(0x8, 4, 0);                                        \
    __builtin_amdgcn_s_setprio(0);                                           \
    __builtin_amdgcn_s_barrier();          /* bar_A */                       \
    __builtin_amdgcn_sched_barrier(0);                                       \
    /* S2: stage A0(t+2) + B1(t+2) -> buf P (readers fenced by bar_A) */     \
    GL(a0q0, (P)*32768);                                                     \
    GL(a0q1, (P)*32768 + 1024);                                              \
    GL(b1q0, 65536 + (P)*32768 + 16384);                                     \
    GL(b1q1, 65536 + (P)*32768 + 16384 + 1024);                              \
    /* Q2 cluster: MFMA(afrA,bfr23) ∥ read afrB = A1(t) */                   \
    __builtin_amdgcn_s_setprio(1);                                           \
    _Pragma("unroll") for (int mm = 0; mm < 4; mm++) {                       \
      afrB[mm][0] = *(const bf16x8*)(vA0 + (P)*32768 + 16384 + mm*2048);     \
      afrB[mm][1] = *(const bf16x8*)(vA1 + (P)*32768 + 16384 + mm*2048);     \
    }                                                                        \
    _Pragma("unroll") for (int mm = 0; mm < 4; mm++)                         \
      _Pragma("unroll") for (int nn = 2; nn < 4; nn++) {                     \
        acc[mm][nn] = MFMA(afrA[mm][0], bfr[nn][0], acc[mm][nn], 0, 0, 0);   \
        acc[mm][nn] = MFMA(afrA[mm][1], bfr[nn][1], acc[mm][nn], 0, 0, 0);   \
      }                                                                      \
    SGB(0x100, 2, 0); SGB(0x8, 4, 0);                                        \
    SGB(0x100, 2, 0); SGB(0x8, 4, 0);                                        \
    SGB(0x100, 2, 0); SGB(0x8, 4, 0);                                        \
    SGB(0x100, 2, 0); SGB(0x8, 4, 0);                                        \
    __builtin_amdgcn_s_setprio(0);                                           \
    /* S3: stage B0(t+2) -> buf P (bfr01(t) reads drained by Q1 MFMAs) */    \
    GL(b0q0, 65536 + (P)*32768);                                             \
    GL(b0q1, 65536 + (P)*32768 + 1024);                                      \
    /* Q3 cluster: MFMA(afrB,bfr01), register-only */                        \
    __builtin_amdgcn_s_setprio(1);                                           \
    _Pragma("unroll") for (int mm = 0; mm < 4; mm++)                         \
      _Pragma("unroll") for (int nn = 0; nn < 2; nn++) {                     \
        acc[4+mm][nn] = MFMA(afrB[mm][0], bfr[nn][0], acc[4+mm][nn], 0, 0, 0);\
        acc[4+mm][nn] = MFMA(afrB[mm][1], bfr[nn][1], acc[4+mm][nn], 0, 0, 0);\
      }                                                                      \
    __builtin_amdgcn_s_setprio(0);                                           \
    /* gate: drain tile t+1's 8 loads (aged 1 full iter); keep t+2's 6 */    \
    asm volatile("s_waitcnt vmcnt(6)" ::: "memory");                         \
    __builtin_amdgcn_s_barrier();          /* bar_B */                       \
    __builtin_amdgcn_sched_barrier(0);                                       \
    /* S4: stage A1(t+2) -> buf P (afrB(t) reads drained pre-bar_B) */       \
    GL(a1q0, (P)*32768 + 16384);                                             \
    GL(a1q1, (P)*32768 + 16384 + 1024);                                      \
    /* Q4 cluster: MFMA(afrB,bfr23) ∥ read afrA,bfr01 of tile t+1 */         \
    __builtin_amdgcn_s_setprio(1);                                           \
    _Pragma("unroll") for (int mm = 0; mm < 4; mm++) {                       \
      afrA[mm][0] = *(const bf16x8*)(vA0 + ((P)^1)*32768 + mm*2048);         \
      afrA[mm][1] = *(const bf16x8*)(vA1 + ((P)^1)*32768 + mm*2048);         \
    }                                                                        \
    _Pragma("unroll") for (int nn = 0; nn < 2; nn++) {                       \
      bfr[nn][0] = *(const bf16x8*)(vB0 + ((P)^1)*32768 + nn*2048);          \
      bfr[nn][1] = *(const bf16x8*)(vB1 + ((P)^1)*32768 + nn*2048);          \
    }                                                                        \
    _Pragma("unroll") for (int mm = 0; mm < 4; mm++)                         \
      _Pragma("unroll") for (int nn = 2; nn < 4; nn++) {                     \
        acc[4+mm][nn] = MFMA(afrB[mm][0], bfr[nn][0], acc[4+mm][nn], 0, 0, 0);\
        acc[4+mm][nn] = MFMA(afrB[mm][1], bfr[nn][1], acc[4+mm][nn], 0, 0, 0);\
      }                                                                      \
    SGB(0x100, 3, 0); SGB(0x8, 4, 0);                                        \
    SGB(0x100, 3, 0); SGB(0x8, 4, 0);                                        \
    SGB(0x100, 3, 0); SGB(0x8, 4, 0);                                        \
    SGB(0x100, 3, 0); SGB(0x8, 4, 0);                                        \
    __builtin_amdgcn_s_setprio(0);                                           \
    a0q0 += 64; a0q1 += 64; a1q0 += 64; a1q1 += 64;                          \
    b0q0 += 64; b0q1 += 64; b1q0 += 64; b1q1 += 64;                          \
  }

  for (int it = 0; it < NT / 2; ++it) {
    BODY(0)
    BODY(1)
  }
#undef BODY
#undef GL

  // ---- drain outstanding staging loads (also orders Cin/bias below) ----
  asm volatile("s_waitcnt vmcnt(0)" ::: "memory");

  // ---- epilogue: register-only gates (lane owns all 4 gates of unit U).
  //      Cin/bias loaded post-loop: no registers held across the main loop.
  const int U = (bcol >> 2) + wc * 16 + lane16;     // unit owned by this lane
  const float* cinp = Cin + (size_t)(brow + wr * 128 + kg * 4) * H_DIM + U;
  float cin[32];
#pragma unroll
  for (int m = 0; m < 8; m++)
#pragma unroll
    for (int r = 0; r < 4; r++)
      cin[m * 4 + r] = cinp[(size_t)(m * 16 + r) * H_DIM];
  float bv[4];
#pragma unroll
  for (int nn = 0; nn < 4; nn++)
    bv[nn] = bias[bcol + wc * 64 + nn * 16 + lane16];

  float* hp = Hout + (size_t)(brow + wr * 128 + kg * 4) * H_DIM + U;
  float* cp = Cout + (size_t)(brow + wr * 128 + kg * 4) * H_DIM + U;
#pragma unroll
  for (int m = 0; m < 8; m++)
#pragma unroll
    for (int r = 0; r < 4; r++) {
      float Ig = sigm(acc[m][0][r] + bv[0]);
      float Fg = sigm(acc[m][1][r] + bv[1]);
      float Gg = tanh_fast(acc[m][2][r] + bv[2]);
      float Og = sigm(acc[m][3][r] + bv[3]);
      float cn = Fg * cin[m * 4 + r] + Ig * Gg;
      size_t off = (size_t)(m * 16 + r) * H_DIM;
      hp[off] = Og * tanh_fast(cn);
      cp[off] = cn;
    }
}

extern "C" void kernel_launch(void* const* d_in, const int* in_sizes, int n_in,
                              void* d_out, int out_size, void* d_ws, size_t ws_size,
                              hipStream_t stream) {
  const float* x  = (const float*)d_in[0];
  const float* h  = (const float*)d_in[1];
  const float* c  = (const float*)d_in[2];
  const float* Wi = (const float*)d_in[3];
  const float* bi = (const float*)d_in[4];
  const float* Wh = (const float*)d_in[5];
  const float* bh = (const float*)d_in[6];

  float* out  = (float*)d_out;
  float* Hout = out;
  float* Cout = out + (size_t)BATCH * H_DIM;

  // workspace layout: A bf16 (32 MiB) | Bt bf16 (16 MiB) | bias f32 (16 KiB)
  unsigned short* Abf = (unsigned short*)d_ws;
  unsigned short* Btb = (unsigned short*)((char*)d_ws + 33554432);
  float*          bsf = (float*)((char*)d_ws + 50331648);

  conv_a<<<2048, 256, 0, stream>>>(x, h, Abf);
  conv_b<<<dim3(64, 128), dim3(32, 8), 0, stream>>>(Wi, Wh, Btb);
  conv_bias<<<16, 256, 0, stream>>>(bi, bh, bsf);
  lstm_gemm<<<512, 512, 0, stream>>>(Abf, Btb, bsf, c, Hout, Cout);
}

// Round 12
// 150.596 us; speedup vs baseline: 1.3551x; 1.0445x over previous
//
#include <hip/hip_runtime.h>
#include <stdint.h>

#define IN_DIM 1024
#define H_DIM  1024
#define BATCH  8192
#define KDIM   2048   // IN + H
#define NDIM   4096   // 4*H
#define BM     256
#define BN     256
#define BK     64
#define NT     (KDIM / BK)   // 32 K-tiles

typedef __bf16 bf16x8 __attribute__((ext_vector_type(8)));
typedef float  f32x4  __attribute__((ext_vector_type(4)));
typedef unsigned int u32;

static __device__ __forceinline__ unsigned short f2bf(float f) {
  u32 u = __builtin_bit_cast(u32, f);
  u += 0x7FFFu + ((u >> 16) & 1u);   // round-to-nearest-even
  return (unsigned short)(u >> 16);
}

static __device__ __forceinline__ float sigm(float x) {
  return 1.0f / (1.0f + __expf(-x));
}
static __device__ __forceinline__ float tanh_fast(float x) {
  float e = __expf(-2.0f * fabsf(x));     // in (0,1], no overflow
  float t = (1.0f - e) / (1.0f + e);
  return copysignf(t, x);
}

// ---- fused prep: one dispatch does A-convert, Bt-permute, bias ----
//   blocks [0,2048)        : A = [x|h] -> bf16 [BATCH][KDIM]
//   blocks [2048,10240)    : Bt[j][k] = W[k][c], gate-contiguous permutation
//                            c = g*1024+u -> j = (u>>4)*64 + g*16 + (u&15)
//   blocks [10240,10256)   : bias[j] = bi[c(j)] + bh[c(j)]
__global__ void prep_all(const float* __restrict__ x, const float* __restrict__ h,
                         const float* __restrict__ Wi, const float* __restrict__ Wh,
                         const float* __restrict__ bi, const float* __restrict__ bh,
                         unsigned short* __restrict__ A,
                         unsigned short* __restrict__ Bt,
                         float* __restrict__ bias) {
  __shared__ float tile[32][33];
  const int b = blockIdx.x;
  const int t = threadIdx.x;

  if (b < 2048) {
    const int total = BATCH * KDIM / 4;
    for (int i = b * 256 + t; i < total; i += 2048 * 256) {
      int bb = i >> 9;             // 512 quads per row
      int k = (i & 511) << 2;
      const float* src = (k < IN_DIM) ? (x + (size_t)bb * IN_DIM + k)
                                      : (h + (size_t)bb * H_DIM + (k - IN_DIM));
      float4 v = *reinterpret_cast<const float4*>(src);
      ushort4 o;
      o.x = f2bf(v.x); o.y = f2bf(v.y); o.z = f2bf(v.z); o.w = f2bf(v.w);
      *reinterpret_cast<ushort4*>(A + (size_t)bb * KDIM + k) = o;
    }
  } else if (b < 10240) {
    int bb = b - 2048;
    int k0 = (bb & 63) * 32;           // k of combined [Wi;Wh]
    int c0 = (bb >> 6) * 32;           // orig col
    int tx = t & 31;
    int ty = t >> 5;                   // 0..7
    const float* src = (k0 < IN_DIM) ? (Wi + (size_t)k0 * NDIM)
                                     : (Wh + (size_t)(k0 - IN_DIM) * NDIM);
    for (int i = 0; i < 4; i++) {
      int r = ty + 8 * i;
      tile[r][tx] = src[(size_t)r * NDIM + c0 + tx];
    }
    __syncthreads();
    int g = c0 >> 10;                  // gate index (tile doesn't straddle)
    int ubase = c0 & 1023;
    for (int i = 0; i < 4; i++) {
      int cc = ty + 8 * i;
      int u = ubase + cc;
      int j = ((u >> 4) << 6) + (g << 4) + (u & 15);
      Bt[(size_t)j * KDIM + k0 + tx] = f2bf(tile[tx][cc]);
    }
  } else {
    int j = (b - 10240) * 256 + t;     // < 4096
    int u = ((j >> 6) << 4) + (j & 15);
    int g = (j >> 4) & 3;
    int c = (g << 10) + u;
    bias[j] = bi[c] + bh[c];
  }
}

// ------- 256x256 GEMM, 2-barrier/K-tile pipeline + fused LSTM epilogue -------
// (R9 schedule verbatim: best measured — 129 µs, MfmaUtil 48%, 0 conflicts)
static __device__ __forceinline__ void gload_lds16(const void* g, void* l) {
  __builtin_amdgcn_global_load_lds(
      (const __attribute__((address_space(1))) u32*)g,
      (__attribute__((address_space(3))) u32*)l, 16, 0, 0);
}

#define MFMA __builtin_amdgcn_mfma_f32_16x16x32_bf16
#define SGB  __builtin_amdgcn_sched_group_barrier
// LLVM SchedGroupMask: MFMA=0x8, DS_READ=0x100

__launch_bounds__(512, 2)
__global__ void lstm_gemm(const unsigned short* __restrict__ A,
                          const unsigned short* __restrict__ Bt,
                          const float* __restrict__ bias,
                          const float* __restrict__ Cin,
                          float* __restrict__ Hout,
                          float* __restrict__ Cout) {
  // LDS: A [2 buf][2 half][128 rows][128B] = 64K | B same = 64K  (128 KiB)
  __shared__ __align__(16) char smem[131072];

  const int t  = threadIdx.x;
  const int l  = t & 63;
  const int w  = t >> 6;           // wave 0-7
  const int lane16 = l & 15;
  const int kg = l >> 4;           // 0-3
  const int wr = w >> 2;           // 0-1  (M)
  const int wc = w & 3;            // 0-3  (N)

  int bid = blockIdx.x;            // 512 blocks (32 M-tiles x 16 N-tiles)
  int swz = (bid & 7) * 64 + (bid >> 3);   // bijective XCD swizzle (512%8==0)
  int brow = (swz >> 4) * BM;
  int bcol = (swz & 15) * BN;

  // ---- staging: slot=(w*2+q)*64+l, LDS linear slot*16; global source chunk
  //      pre-swizzled c = (slot&7) ^ (row&7)  (read side XORs the same) ----
  int slot0 = w * 128 + l, slot1 = slot0 + 64;
  int rih0 = slot0 >> 3, rih1 = slot1 >> 3;
  int c0 = (slot0 & 7) ^ (rih0 & 7), c1 = (slot1 & 7) ^ (rih1 & 7);

  // 8 rolling global pointers (A/B x half0/1 x slot q0/q1), bumped 64 elem/K-tile
  const unsigned short* a0q0 = A + (size_t)(brow + (rih0 >> 6) * 128 + (rih0 & 63)) * KDIM + c0 * 8;
  const unsigned short* a0q1 = A + (size_t)(brow + (rih1 >> 6) * 128 + (rih1 & 63)) * KDIM + c1 * 8;
  const unsigned short* a1q0 = a0q0 + 131072;   // +64 rows
  const unsigned short* a1q1 = a0q1 + 131072;
  const unsigned short* b0q0 = Bt + (size_t)(bcol + (rih0 >> 5) * 64 + (rih0 & 31)) * KDIM + c0 * 8;
  const unsigned short* b0q1 = Bt + (size_t)(bcol + (rih1 >> 5) * 64 + (rih1 & 31)) * KDIM + c1 * 8;
  const unsigned short* b1q0 = b0q0 + 65536;    // +32 rows
  const unsigned short* b1q1 = b0q1 + 65536;

#define GL(gp, loff) gload_lds16((gp), smem + (loff) + w * 2048 + l * 16)

  // ---- per-lane ds_read base addresses; everything else folds to offset: ----
  const int msk = (lane16 & 7) << 4;
  char* vA0 = smem + wr * 8192 + lane16 * 128 + ((kg * 16) ^ msk);
  char* vA1 = smem + wr * 8192 + lane16 * 128 + ((64 + kg * 16) ^ msk);
  char* vB0 = smem + 65536 + wc * 4096 + lane16 * 128 + ((kg * 16) ^ msk);
  char* vB1 = smem + 65536 + wc * 4096 + lane16 * 128 + ((64 + kg * 16) ^ msk);

  f32x4 acc[8][4];
#pragma unroll
  for (int m = 0; m < 8; m++)
#pragma unroll
    for (int n = 0; n < 4; n++) acc[m][n] = (f32x4){0.f, 0.f, 0.f, 0.f};

  // ---- prologue: tile0 full -> buf0 ; tile1 {A0,B0} -> buf1 ----
  GL(a0q0, 0);                 GL(a0q1, 1024);
  GL(b0q0, 65536);             GL(b0q1, 65536 + 1024);
  GL(a1q0, 16384);             GL(a1q1, 16384 + 1024);
  GL(b1q0, 65536 + 16384);     GL(b1q1, 65536 + 16384 + 1024);
  GL(a0q0 + 64, 32768);        GL(a0q1 + 64, 32768 + 1024);
  GL(b0q0 + 64, 65536 + 32768);GL(b0q1 + 64, 65536 + 32768 + 1024);
  asm volatile("s_waitcnt vmcnt(4)" ::: "memory");   // tile0 landed
  __builtin_amdgcn_s_barrier();
  __builtin_amdgcn_sched_barrier(0);
  // A1(1) -> buf1 (post-barrier slot of the virtual body(-1))
  GL(a1q0 + 64, 32768 + 16384); GL(a1q1 + 64, 32768 + 16384 + 1024);

  // ---- operand registers (ping-pong lifetimes across quadrant clusters) ----
  bf16x8 afrA[4][2], afrB[4][2], bfr[4][2];

  // prime: afrA = A0(0), bfr01 = B0(0) from buf0
#pragma unroll
  for (int mm = 0; mm < 4; mm++) {
    afrA[mm][0] = *(const bf16x8*)(vA0 + mm * 2048);
    afrA[mm][1] = *(const bf16x8*)(vA1 + mm * 2048);
  }
#pragma unroll
  for (int nn = 0; nn < 2; nn++) {
    bfr[nn][0] = *(const bf16x8*)(vB0 + nn * 2048);
    bfr[nn][1] = *(const bf16x8*)(vB1 + nn * 2048);
  }
  // roll: a*,b0 -> tile2 ; b1 -> tile1
  a0q0 += 128; a0q1 += 128; a1q0 += 128; a1q1 += 128;
  b0q0 += 128; b0q1 += 128; b1q0 += 64;  b1q1 += 64;

  // ---- 2-barrier K-tile body (R9). Sync: bar_A after Q1 cluster;
  //      vmcnt(4)+bar_B before Q4 cluster. Hazards traced; sched_barrier(0)
  //      after each barrier stops GL/ds_read hoisting (rule #18).
#define BODY(P)                                                              \
  {                                                                          \
    /* S1: stage B1(t+1) -> buf^1 (region's last reader drained pre-bar_B) */\
    GL(b1q0, 65536 + ((P)^1)*32768 + 16384);                                 \
    GL(b1q1, 65536 + ((P)^1)*32768 + 16384 + 1024);                          \
    /* Q1 cluster: MFMA(afrA,bfr01) ∥ read bfr23(t) */                       \
    __builtin_amdgcn_s_setprio(1);                                           \
    _Pragma("unroll") for (int nn = 2; nn < 4; nn++) {                       \
      bfr[nn][0] = *(const bf16x8*)(vB0 + (P)*32768 + 16384 + (nn-2)*2048);  \
      bfr[nn][1] = *(const bf16x8*)(vB1 + (P)*32768 + 16384 + (nn-2)*2048);  \
    }                                                                        \
    _Pragma("unroll") for (int mm = 0; mm < 4; mm++)                         \
      _Pragma("unroll") for (int nn = 0; nn < 2; nn++) {                     \
        acc[mm][nn] = MFMA(afrA[mm][0], bfr[nn][0], acc[mm][nn], 0, 0, 0);   \
        acc[mm][nn] = MFMA(afrA[mm][1], bfr[nn][1], acc[mm][nn], 0, 0, 0);   \
      }                                                                      \
    SGB(0x100, 1, 0); SGB(0x8, 4, 0);                                        \
    SGB(0x100, 1, 0); SGB(0x8, 4, 0);                                        \
    SGB(0x100, 1, 0); SGB(0x8, 4, 0);                                        \
    SGB(0x100, 1, 0); SGB(0x8, 4, 0);                                        \
    __builtin_amdgcn_s_setprio(0);                                           \
    __builtin_amdgcn_s_barrier();          /* bar_A */                       \
    __builtin_amdgcn_sched_barrier(0);                                       \
    /* S2: stage A0(t+2) -> buf P (afrA(t) reads drained by Q1 MFMAs) */     \
    GL(a0q0, (P)*32768);                                                     \
    GL(a0q1, (P)*32768 + 1024);                                              \
    /* Q2 cluster: MFMA(afrA,bfr23) ∥ read afrB = A1(t) */                   \
    __builtin_amdgcn_s_setprio(1);                                           \
    _Pragma("unroll") for (int mm = 0; mm < 4; mm++) {                       \
      afrB[mm][0] = *(const bf16x8*)(vA0 + (P)*32768 + 16384 + mm*2048);     \
      afrB[mm][1] = *(const bf16x8*)(vA1 + (P)*32768 + 16384 + mm*2048);     \
    }                                                                        \
    _Pragma("unroll") for (int mm = 0; mm < 4; mm++)                         \
      _Pragma("unroll") for (int nn = 2; nn < 4; nn++) {                     \
        acc[mm][nn] = MFMA(afrA[mm][0], bfr[nn][0], acc[mm][nn], 0, 0, 0);   \
        acc[mm][nn] = MFMA(afrA[mm][1], bfr[nn][1], acc[mm][nn], 0, 0, 0);   \
      }                                                                      \
    SGB(0x100, 2, 0); SGB(0x8, 4, 0);                                        \
    SGB(0x100, 2, 0); SGB(0x8, 4, 0);                                        \
    SGB(0x100, 2, 0); SGB(0x8, 4, 0);                                        \
    SGB(0x100, 2, 0); SGB(0x8, 4, 0);                                        \
    __builtin_amdgcn_s_setprio(0);                                           \
    /* S3: stage B0(t+2) -> buf P (bfr01(t) reads drained by Q1 MFMAs) */    \
    GL(b0q0, 65536 + (P)*32768);                                             \
    GL(b0q1, 65536 + (P)*32768 + 1024);                                      \
    /* Q3 cluster: MFMA(afrB,bfr01), register-only */                        \
    __builtin_amdgcn_s_setprio(1);                                           \
    _Pragma("unroll") for (int mm = 0; mm < 4; mm++)                         \
      _Pragma("unroll") for (int nn = 0; nn < 2; nn++) {                     \
        acc[4+mm][nn] = MFMA(afrB[mm][0], bfr[nn][0], acc[4+mm][nn], 0, 0, 0);\
        acc[4+mm][nn] = MFMA(afrB[mm][1], bfr[nn][1], acc[4+mm][nn], 0, 0, 0);\
      }                                                                      \
    __builtin_amdgcn_s_setprio(0);                                           \
    /* gate: tile t+1 fully landed (FIFO: only A0,B0(t+2) stay outstanding) */\
    asm volatile("s_waitcnt vmcnt(4)" ::: "memory");                         \
    __builtin_amdgcn_s_barrier();          /* bar_B */                       \
    __builtin_amdgcn_sched_barrier(0);                                       \
    /* S4: stage A1(t+2) -> buf P (afrB(t) reads drained pre-bar_B) */       \
    GL(a1q0, (P)*32768 + 16384);                                             \
    GL(a1q1, (P)*32768 + 16384 + 1024);                                      \
    /* Q4 cluster: MFMA(afrB,bfr23) ∥ read afrA,bfr01 of tile t+1 */         \
    __builtin_amdgcn_s_setprio(1);                                           \
    _Pragma("unroll") for (int mm = 0; mm < 4; mm++) {                       \
      afrA[mm][0] = *(const bf16x8*)(vA0 + ((P)^1)*32768 + mm*2048);         \
      afrA[mm][1] = *(const bf16x8*)(vA1 + ((P)^1)*32768 + mm*2048);         \
    }                                                                        \
    _Pragma("unroll") for (int nn = 0; nn < 2; nn++) {                       \
      bfr[nn][0] = *(const bf16x8*)(vB0 + ((P)^1)*32768 + nn*2048);          \
      bfr[nn][1] = *(const bf16x8*)(vB1 + ((P)^1)*32768 + nn*2048);          \
    }                                                                        \
    _Pragma("unroll") for (int mm = 0; mm < 4; mm++)                         \
      _Pragma("unroll") for (int nn = 2; nn < 4; nn++) {                     \
        acc[4+mm][nn] = MFMA(afrB[mm][0], bfr[nn][0], acc[4+mm][nn], 0, 0, 0);\
        acc[4+mm][nn] = MFMA(afrB[mm][1], bfr[nn][1], acc[4+mm][nn], 0, 0, 0);\
      }                                                                      \
    SGB(0x100, 3, 0); SGB(0x8, 4, 0);                                        \
    SGB(0x100, 3, 0); SGB(0x8, 4, 0);                                        \
    SGB(0x100, 3, 0); SGB(0x8, 4, 0);                                        \
    SGB(0x100, 3, 0); SGB(0x8, 4, 0);                                        \
    __builtin_amdgcn_s_setprio(0);                                           \
    a0q0 += 64; a0q1 += 64; a1q0 += 64; a1q1 += 64;                          \
    b0q0 += 64; b0q1 += 64; b1q0 += 64; b1q1 += 64;                          \
  }

  for (int it = 0; it < NT / 2; ++it) {
    BODY(0)
    BODY(1)
  }
#undef BODY
#undef GL

  // ---- drain outstanding staging loads (also orders Cin/bias below) ----
  asm volatile("s_waitcnt vmcnt(0)" ::: "memory");

  // ---- epilogue: register-only gates (lane owns all 4 gates of unit U).
  //      Cin/bias loaded post-loop: no registers held across the main loop.
  const int U = (bcol >> 2) + wc * 16 + lane16;     // unit owned by this lane
  const float* cinp = Cin + (size_t)(brow + wr * 128 + kg * 4) * H_DIM + U;
  float cin[32];
#pragma unroll
  for (int m = 0; m < 8; m++)
#pragma unroll
    for (int r = 0; r < 4; r++)
      cin[m * 4 + r] = cinp[(size_t)(m * 16 + r) * H_DIM];
  float bv[4];
#pragma unroll
  for (int nn = 0; nn < 4; nn++)
    bv[nn] = bias[bcol + wc * 64 + nn * 16 + lane16];

  float* hp = Hout + (size_t)(brow + wr * 128 + kg * 4) * H_DIM + U;
  float* cp = Cout + (size_t)(brow + wr * 128 + kg * 4) * H_DIM + U;
#pragma unroll
  for (int m = 0; m < 8; m++)
#pragma unroll
    for (int r = 0; r < 4; r++) {
      float Ig = sigm(acc[m][0][r] + bv[0]);
      float Fg = sigm(acc[m][1][r] + bv[1]);
      float Gg = tanh_fast(acc[m][2][r] + bv[2]);
      float Og = sigm(acc[m][3][r] + bv[3]);
      float cn = Fg * cin[m * 4 + r] + Ig * Gg;
      size_t off = (size_t)(m * 16 + r) * H_DIM;
      hp[off] = Og * tanh_fast(cn);
      cp[off] = cn;
    }
}

extern "C" void kernel_launch(void* const* d_in, const int* in_sizes, int n_in,
                              void* d_out, int out_size, void* d_ws, size_t ws_size,
                              hipStream_t stream) {
  const float* x  = (const float*)d_in[0];
  const float* h  = (const float*)d_in[1];
  const float* c  = (const float*)d_in[2];
  const float* Wi = (const float*)d_in[3];
  const float* bi = (const float*)d_in[4];
  const float* Wh = (const float*)d_in[5];
  const float* bh = (const float*)d_in[6];

  float* out  = (float*)d_out;
  float* Hout = out;
  float* Cout = out + (size_t)BATCH * H_DIM;

  // workspace layout: A bf16 (32 MiB) | Bt bf16 (16 MiB) | bias f32 (16 KiB)
  unsigned short* Abf = (unsigned short*)d_ws;
  unsigned short* Btb = (unsigned short*)((char*)d_ws + 33554432);
  float*          bsf = (float*)((char*)d_ws + 50331648);

  prep_all<<<10256, 256, 0, stream>>>(x, h, Wi, Wh, bi, bh, Abf, Btb, bsf);
  lstm_gemm<<<512, 512, 0, stream>>>(Abf, Btb, bsf, c, Hout, Cout);
}